// Round 11
// baseline (119.043 us; speedup 1.0000x reference)
//
#include <hip/hip_runtime.h>
#include <hip/hip_bf16.h>
#include <math.h>

#define N 8192
#define D 256
#define MARGIN 0.3f
#define EPS 1e-12f

#define BT 128                             // block tile (i and j)
#define NJB (N / BT)                       // 64 tile-blocks per dim
#define TOTAL_TRI (NJB * (NJB + 1) / 2)    // 2080 upper-triangle tiles = 8 * 260

typedef __attribute__((ext_vector_type(8))) short short8;   // 8 bf16 in 4 VGPRs
typedef __attribute__((ext_vector_type(4))) float floatx4;  // MFMA C/D

static __device__ inline ushort f2bf(float f) {
    __hip_bfloat16 h = __float2bfloat16(f);
    return *reinterpret_cast<ushort*>(&h);
}

// fn16t layout (MFMA-fragment-tiled): element (row r, k) lives at
//   chunk c = (r>>4)*8 + (k>>5), offset (((k>>3)&3)*16 + (r&15))*8 + (k&7)
// so a wave (lane = quad*16+l15) loads fragment (rows g*16..+15, k-step kk) as ONE contiguous
// 1KB transaction: *(short8*)(fn16t + c*512 + lane*8).

// ---------------- Kernel 1: L2 normalize -> bf16 in tiled layout (16 rows/block) -------------
__global__ __launch_bounds__(256) void normalize_kernel(const float* __restrict__ x,
                                                        ushort* __restrict__ fn16t,
                                                        float* __restrict__ out) {
    __shared__ ushort lnorm[16][256];     // 8 KB
    const int g    = blockIdx.x;          // group of 16 rows
    const int t    = threadIdx.x;
    const int w    = t >> 6;
    const int lane = t & 63;
    if (g == 0 && t == 0) out[0] = 0.0f;

    #pragma unroll
    for (int rr = 0; rr < 4; rr++) {
        const int rl  = w * 4 + rr;       // local row 0..15
        const int row = g * 16 + rl;
        float4 v = ((const float4*)(x + (size_t)row * D))[lane];
        float s = v.x * v.x + v.y * v.y + v.z * v.z + v.w * v.w;
        #pragma unroll
        for (int off = 32; off; off >>= 1) s += __shfl_down(s, off);
        s = __shfl(s, 0);
        const float inv = 1.0f / fmaxf(sqrtf(s), 1e-12f);
        ushort4 b;
        b.x = f2bf(v.x * inv); b.y = f2bf(v.y * inv);
        b.z = f2bf(v.z * inv); b.w = f2bf(v.w * inv);
        *(ushort4*)(&lnorm[rl][lane * 4]) = b;
    }
    __syncthreads();
    // write tiled: thread t covers chunk kk = t>>5, two lane-slots p = (t&31)*2 + {0,1}
    const int kk = t >> 5;
    const int pp = (t & 31) * 2;
    ushort* base = fn16t + ((size_t)g * 8 + kk) * 512;
    #pragma unroll
    for (int e = 0; e < 2; e++) {
        const int p    = pp + e;
        const int quad = p >> 4;
        const int l15  = p & 15;
        *(short8*)(base + p * 8) = *(const short8*)(&lnorm[l15][kk * 32 + quad * 8]);
    }
}

// ---------------- Kernel 2: triangular MFMA gram, 8 waves x 64x32, barrier-free --------------
// R11 discriminating experiment. Champion (43.4us, 4 waves x 128x128/4) is stuck at 12
// waves/CU (acc 64 + frags 32 + addr ~40 = 136 regs -> 3 waves/SIMD hard ceiling; R8/R10
// proved any cap below that spills acc). Two candidate models: (A) wave-latency-bound
// (time ~ per-wave loads x latency / resident waves) vs (B) per-CU request throughput
// (~21 B/cy). This geometry moves them OPPOSITE ways: 8 waves of 64x32 tiles (wi=w>>2 half,
// wj=w&3 quarter): per wave 6 loads + 8 MFMA per step, acc 32 + frags 24 + misc ~35 -> ~90
// regs, launch_bounds(512,4) caps 128 (no spill possible), 2 blocks/CU = 16 waves/CU.
// Requests 1.5x (A chunks read 4x, L1 may absorb). Model A predicts ~24-30us; B ~60us.
// Row-side reduce: in-lane n-fold then 4x shfl_xor over l15 (32-col quarter), rowP[128][5]
// LDS, folded by threads 128..255. Col-side unchanged. Reductions on g (post-norm
// ||f||^2==1, d2=2-2g monotone dec).
__global__ __launch_bounds__(512, 4) void gram_kernel(const ushort* __restrict__ fn16t,
                                                      const int* __restrict__ lab,
                                                      float* __restrict__ gp_part,
                                                      float* __restrict__ gn_part) {
    __shared__ float rowP[BT][5], rowN[BT][5]; // 5 KB: [irow][wj] row-side partials (pad 5)
    __shared__ float cGp[BT][2], cGn[BT][2];   // 2 KB: [col][wi] col-side partials

    // XCD swizzle then triangular decode (row-major over jb >= ib)
    const int bidx = blockIdx.x;
    const int idx  = (bidx & 7) * 260 + (bidx >> 3);
    const float c = 2.0f * NJB + 1.0f;
    int ib = (int)((c - sqrtf(c * c - 8.0f * (float)idx)) * 0.5f);
    while (ib > 0 && idx < ib * NJB - ib * (ib - 1) / 2) ib--;
    while (idx >= (ib + 1) * NJB - (ib + 1) * ib / 2) ib++;
    const int jb = ib + (idx - (ib * NJB - ib * (ib - 1) / 2));
    const bool offdiag = (jb > ib);
    const int i0 = ib * BT, j0 = jb * BT;

    const int t    = threadIdx.x;
    const int w    = t >> 6;                    // 0..7
    const int lane = t & 63;
    const int wi   = w >> 2, wj = w & 3;        // 2 row-halves x 4 col-quarters
    const int quad = lane >> 4;
    const int l15  = lane & 15;

    // fragment base pointers (group stride = 4096 ushorts)
    const ushort* pA[4];
    const ushort* pB[2];
    #pragma unroll
    for (int m = 0; m < 4; m++)
        pA[m] = fn16t + ((size_t)(ib * 8 + wi * 4 + m)) * 4096 + lane * 8;
    #pragma unroll
    for (int n = 0; n < 2; n++)
        pB[n] = fn16t + ((size_t)(jb * 8 + wj * 2 + n)) * 4096 + lane * 8;

    floatx4 acc[4][2];
    #pragma unroll
    for (int m = 0; m < 4; m++)
        #pragma unroll
        for (int n = 0; n < 2; n++)
            acc[m][n] = (floatx4){0.f, 0.f, 0.f, 0.f};

    // K-loop: 8 steps of K=32, contiguous 1KB fragment loads, no barriers
    #pragma unroll
    for (int kk = 0; kk < 8; kk++) {
        short8 af[4], bf_[2];
        #pragma unroll
        for (int m = 0; m < 4; m++) af[m]  = *(const short8*)(pA[m] + kk * 512);
        #pragma unroll
        for (int n = 0; n < 2; n++) bf_[n] = *(const short8*)(pB[n] + kk * 512);
        #pragma unroll
        for (int m = 0; m < 4; m++)
            #pragma unroll
            for (int n = 0; n < 2; n++)
                acc[m][n] = __builtin_amdgcn_mfma_f32_16x16x32_bf16(af[m], bf_[n], acc[m][n], 0, 0, 0);
    }

    // ---- epilogue on g. C/D layout: col = l15 (tile col wj*32+n*16+l15), row = quad*4 + reg.
    int labj[2];
    #pragma unroll
    for (int n = 0; n < 2; n++) labj[n] = lab[j0 + wj * 32 + n * 16 + l15];
    float gpc[2], gnc[2];
    #pragma unroll
    for (int n = 0; n < 2; n++) { gpc[n] = INFINITY; gnc[n] = -INFINITY; }

    #pragma unroll
    for (int m = 0; m < 4; m++) {
        const int4 li4 = *(const int4*)(lab + i0 + wi * 64 + m * 16 + quad * 4);
        const int labi[4] = {li4.x, li4.y, li4.z, li4.w};
        #pragma unroll
        for (int r = 0; r < 4; r++) {
            float pr = INFINITY, nr = -INFINITY;
            #pragma unroll
            for (int n = 0; n < 2; n++) {
                const float g = acc[m][n][r];
                const bool same = (labi[r] == labj[n]);
                const float selp = same ? g : INFINITY;
                const float seln = same ? -INFINITY : g;
                pr = fminf(pr, selp);           nr = fmaxf(nr, seln);
                gpc[n] = fminf(gpc[n], selp);   gnc[n] = fmaxf(gnc[n], seln);
            }
            if (offdiag) {                      // row-side: fold 16 cols via l15 shuffle tree
                pr = fminf(pr, __shfl_xor(pr, 1));  pr = fminf(pr, __shfl_xor(pr, 2));
                pr = fminf(pr, __shfl_xor(pr, 4));  pr = fminf(pr, __shfl_xor(pr, 8));
                nr = fmaxf(nr, __shfl_xor(nr, 1));  nr = fmaxf(nr, __shfl_xor(nr, 2));
                nr = fmaxf(nr, __shfl_xor(nr, 4));  nr = fmaxf(nr, __shfl_xor(nr, 8));
                if (l15 == 0) {
                    const int irow = wi * 64 + m * 16 + quad * 4 + r;
                    rowP[irow][wj] = pr; rowN[irow][wj] = nr;
                }
            }
        }
    }
    // column-side: fold the 4 quads (covers all 64 rows of the wi half)
    #pragma unroll
    for (int n = 0; n < 2; n++) {
        float p = gpc[n], q2 = gnc[n];
        p  = fminf(p,  __shfl_xor(p, 16));  p  = fminf(p,  __shfl_xor(p, 32));
        q2 = fmaxf(q2, __shfl_xor(q2, 16)); q2 = fmaxf(q2, __shfl_xor(q2, 32));
        if (quad == 0) {
            const int col = wj * 32 + n * 16 + l15;
            cGp[col][wi] = p; cGn[col][wi] = q2;
        }
    }
    __syncthreads();
    if (t < BT) {                               // col-side store
        gp_part[(size_t)ib * N + j0 + t] = fminf(cGp[t][0], cGp[t][1]);
        gn_part[(size_t)ib * N + j0 + t] = fmaxf(cGn[t][0], cGn[t][1]);
    } else if (t < 2 * BT && offdiag) {         // row-side fold 4 quarters + store
        const int i = t - BT;
        const float p  = fminf(fminf(rowP[i][0], rowP[i][1]), fminf(rowP[i][2], rowP[i][3]));
        const float nn = fmaxf(fmaxf(rowN[i][0], rowN[i][1]), fmaxf(rowN[i][2], rowN[i][3]));
        gp_part[(size_t)jb * N + i0 + i] = p;
        gn_part[(size_t)jb * N + i0 + i] = nn;
    }
}

// ---------------- Kernel 3: fold slots, sqrt, relu, mean — 256 blocks, coalesced ------------
__global__ __launch_bounds__(256) void reduce_kernel(const float* __restrict__ gp_part,
                                                     const float* __restrict__ gn_part,
                                                     float* __restrict__ out) {
    __shared__ float redp[32][5], redn[32][5];
    const int t  = threadIdx.x;
    const int r  = blockIdx.x * 32 + (t & 31);   // 256 blocks x 32 rows
    const int sg = t >> 5;                        // slot group 0..7
    float gp = INFINITY, gn = -INFINITY;
    #pragma unroll
    for (int q = 0; q < 8; q++) {
        const int s = sg * 8 + q;
        gp = fminf(gp, gp_part[(size_t)s * N + r]);
        gn = fmaxf(gn, gn_part[(size_t)s * N + r]);
    }
    gp = fminf(gp, __shfl_xor(gp, 32));
    gn = fmaxf(gn, __shfl_xor(gn, 32));
    const int w = t >> 6;
    if ((t & 63) < 32) { redp[t & 31][w] = gp; redn[t & 31][w] = gn; }
    __syncthreads();
    if (t < 32) {
        const float p  = fminf(fminf(redp[t][0], redp[t][1]), fminf(redp[t][2], redp[t][3]));
        const float nn = fmaxf(fmaxf(redn[t][0], redn[t][1]), fmaxf(redn[t][2], redn[t][3]));
        const float dp = sqrtf(fmaxf(2.0f - 2.0f * p,  EPS));  // hardest_pos distance
        const float dn = sqrtf(fmaxf(2.0f - 2.0f * nn, EPS));  // hardest_neg distance
        const float l  = dp - dn + MARGIN;
        float sum = (l > 0.0f) ? l : 0.0f;
        #pragma unroll
        for (int off = 16; off; off >>= 1) sum += __shfl_down(sum, off);
        if (t == 0) atomicAdd(out, sum * (1.0f / (float)N));
    }
}

extern "C" void kernel_launch(void* const* d_in, const int* in_sizes, int n_in,
                              void* d_out, int out_size, void* d_ws, size_t ws_size,
                              hipStream_t stream) {
    const float* x   = (const float*)d_in[0];
    const int*   lab = (const int*)d_in[1];
    float* out = (float*)d_out;

    char* ws = (char*)d_ws;
    ushort* fn16t   = (ushort*)ws;                                  // N*D bf16 = 4 MB (tiled)
    float*  gp_part = (float*)(ws + (size_t)N * D * 2);             // NJB*N floats = 2 MB
    float*  gn_part = gp_part + (size_t)NJB * N;                    // NJB*N floats = 2 MB

    normalize_kernel<<<N / 16, 256, 0, stream>>>(x, fn16t, out);
    gram_kernel<<<TOTAL_TRI, 512, 0, stream>>>(fn16t, lab, gp_part, gn_part);
    reduce_kernel<<<N / 32, 256, 0, stream>>>(gp_part, gn_part, out);
}

// Round 12
// 91.551 us; speedup vs baseline: 1.3003x; 1.3003x over previous
//
#include <hip/hip_runtime.h>
#include <hip/hip_bf16.h>
#include <hip/hip_fp8.h>
#include <math.h>

#define N 8192
#define D 256
#define MARGIN 0.3f
#define EPS 1e-12f

#define BT 128                             // block tile (i and j)
#define NJB (N / BT)                       // 64 tile-blocks per dim
#define TOTAL_TRI (NJB * (NJB + 1) / 2)    // 2080 upper-triangle tiles = 8 * 260

typedef __attribute__((ext_vector_type(4))) float floatx4;  // MFMA C/D
typedef long long fp8x8;                                    // 8 fp8 in 2 VGPRs

static __device__ inline unsigned char f2fp8(float f) {
    __hip_fp8_e4m3 h(f);                   // OCP e4m3fn (gfx950), RNE
    return *reinterpret_cast<unsigned char*>(&h);
}

// fn8t layout (MFMA-fragment-tiled, fp8): element (row r, k) lives at
//   chunk c = (r>>4)*8 + (k>>5), byte offset (((k>>3)&3)*16 + (r&15))*8 + (k&7)
// i.e. chunk = 512 B; wave lane (quad*16+l15) loads its 16x32 fp8 fragment as ONE contiguous
// 512B transaction: *(fp8x8*)(fn8t + c*512 + lane*8). Same k = quad*8+j mapping as the
// verified bf16 16x16x32 fragment (fp8 16x16x32 holds 8 elems/lane in 2 VGPRs).

// ---------------- Kernel 1: L2 normalize -> fp8 e4m3 in tiled layout (16 rows/block) ---------
__global__ __launch_bounds__(256) void normalize_kernel(const float* __restrict__ x,
                                                        unsigned char* __restrict__ fn8t,
                                                        float* __restrict__ out) {
    __shared__ unsigned char lnorm[16][256];  // 4 KB
    const int g    = blockIdx.x;          // group of 16 rows
    const int t    = threadIdx.x;
    const int w    = t >> 6;
    const int lane = t & 63;
    if (g == 0 && t == 0) out[0] = 0.0f;

    #pragma unroll
    for (int rr = 0; rr < 4; rr++) {
        const int rl  = w * 4 + rr;       // local row 0..15
        const int row = g * 16 + rl;
        float4 v = ((const float4*)(x + (size_t)row * D))[lane];
        float s = v.x * v.x + v.y * v.y + v.z * v.z + v.w * v.w;
        #pragma unroll
        for (int off = 32; off; off >>= 1) s += __shfl_down(s, off);
        s = __shfl(s, 0);
        const float inv = 1.0f / fmaxf(sqrtf(s), 1e-12f);
        uchar4 b;
        b.x = f2fp8(v.x * inv); b.y = f2fp8(v.y * inv);
        b.z = f2fp8(v.z * inv); b.w = f2fp8(v.w * inv);
        *(uchar4*)(&lnorm[rl][lane * 4]) = b;
    }
    __syncthreads();
    // write tiled: thread t covers chunk kk = t>>5, two lane-slots p = (t&31)*2 + {0,1}
    const int kk = t >> 5;
    const int pp = (t & 31) * 2;
    unsigned char* base = fn8t + ((size_t)g * 8 + kk) * 512;
    #pragma unroll
    for (int e = 0; e < 2; e++) {
        const int p    = pp + e;
        const int quad = p >> 4;
        const int l15  = p & 15;
        *(fp8x8*)(base + p * 8) = *(const fp8x8*)(&lnorm[l15][kk * 32 + quad * 8]);
    }
}

// ---------------- Kernel 2: triangular MFMA gram (fp8), barrier-free K-loop + rT epilogue ----
// R12: R11's discriminator confirmed the loop is bound by per-CU requested-BYTE service
// (~21 B/cy/CU; occupancy-independent 11-12 waves, schedule-independent R4). Every structural
// lever is falsified (R1/R6 LDS, R3 order, R7/R8/R10 geometry/regs, R9 persistence). The one
// remaining lever: halve requested bytes via fp8 e4m3 fragments. EXACT champion structure
// (43.4us): same tiles, same XCD swizzle, same barrier-free 8-step K-loop (8 fragment loads,
// now 512B each), mfma_f32_16x16x32_fp8_fp8 (same shape, same verified dtype-independent C/D
// layout), same rT epilogue. If byte-bound: ~23-28us. If unchanged: per-instruction wall ->
// bf16 champion is the floor. Reductions on g (post-norm ||f||^2==1, d2=2-2g monotone dec).
__global__ __launch_bounds__(256, 3) void gram_kernel(const unsigned char* __restrict__ fn8t,
                                                      const int* __restrict__ lab,
                                                      float* __restrict__ gp_part,
                                                      float* __restrict__ gn_part) {
    __shared__ float rT[4][BT][17];            // 34816 B; plane = wj*2 + {0:p,1:n}
    __shared__ float cGp[BT][2], cGn[BT][2];   // j-col partials, per wi half

    // XCD swizzle then triangular decode (row-major over jb >= ib)
    const int bidx = blockIdx.x;
    const int idx  = (bidx & 7) * 260 + (bidx >> 3);
    const float c = 2.0f * NJB + 1.0f;
    int ib = (int)((c - sqrtf(c * c - 8.0f * (float)idx)) * 0.5f);
    while (ib > 0 && idx < ib * NJB - ib * (ib - 1) / 2) ib--;
    while (idx >= (ib + 1) * NJB - (ib + 1) * ib / 2) ib++;
    const int jb = ib + (idx - (ib * NJB - ib * (ib - 1) / 2));
    const bool offdiag = (jb > ib);
    const int i0 = ib * BT, j0 = jb * BT;

    const int t    = threadIdx.x;
    const int w    = t >> 6;
    const int lane = t & 63;
    const int wi   = w >> 1, wj = w & 1;        // 2x2 waves, each 64x64
    const int quad = lane >> 4;
    const int l15  = lane & 15;

    // fragment base pointers into the tiled layout (group stride = 4096 BYTES = 8 chunks)
    const unsigned char* pA[4];
    const unsigned char* pB[4];
    #pragma unroll
    for (int m = 0; m < 4; m++)
        pA[m] = fn8t + ((size_t)(ib * 8 + wi * 4 + m)) * 4096 + lane * 8;
    #pragma unroll
    for (int n = 0; n < 4; n++)
        pB[n] = fn8t + ((size_t)(jb * 8 + wj * 4 + n)) * 4096 + lane * 8;

    floatx4 acc[4][4];
    #pragma unroll
    for (int m = 0; m < 4; m++)
        #pragma unroll
        for (int n = 0; n < 4; n++)
            acc[m][n] = (floatx4){0.f, 0.f, 0.f, 0.f};

    // K-loop: 8 steps of K=32, contiguous 512B fragment loads, no barriers
    #pragma unroll
    for (int kk = 0; kk < 8; kk++) {
        fp8x8 af[4], bf_[4];
        #pragma unroll
        for (int m = 0; m < 4; m++) af[m]  = *(const fp8x8*)(pA[m] + kk * 512);
        #pragma unroll
        for (int n = 0; n < 4; n++) bf_[n] = *(const fp8x8*)(pB[n] + kk * 512);
        #pragma unroll
        for (int m = 0; m < 4; m++)
            #pragma unroll
            for (int n = 0; n < 4; n++)
                acc[m][n] = __builtin_amdgcn_mfma_f32_16x16x32_fp8_fp8(af[m], bf_[n], acc[m][n], 0, 0, 0);
    }

    // ---- epilogue on g. C/D layout: col = l15 (tile col wj*64+n*16+l15), row = quad*4 + reg.
    int labj[4];
    #pragma unroll
    for (int n = 0; n < 4; n++) labj[n] = lab[j0 + wj * 64 + n * 16 + l15];
    float gpc[4], gnc[4];
    #pragma unroll
    for (int n = 0; n < 4; n++) { gpc[n] = INFINITY; gnc[n] = -INFINITY; }

    #pragma unroll
    for (int m = 0; m < 4; m++) {
        const int4 li4 = *(const int4*)(lab + i0 + wi * 64 + m * 16 + quad * 4);
        const int labi[4] = {li4.x, li4.y, li4.z, li4.w};
        #pragma unroll
        for (int r = 0; r < 4; r++) {
            float pr = INFINITY, nr = -INFINITY;
            #pragma unroll
            for (int n = 0; n < 4; n++) {
                const float g = acc[m][n][r];
                const bool same = (labi[r] == labj[n]);
                const float selp = same ? g : INFINITY;
                const float seln = same ? -INFINITY : g;
                pr = fminf(pr, selp);           nr = fmaxf(nr, seln);
                gpc[n] = fminf(gpc[n], selp);   gnc[n] = fmaxf(gnc[n], seln);
            }
            if (offdiag) {                      // row-side: LDS transpose, no shuffle chain
                const int irow = wi * 64 + m * 16 + quad * 4 + r;
                rT[(wj << 1) + 0][irow][l15] = pr;
                rT[(wj << 1) + 1][irow][l15] = nr;
            }
        }
    }
    // column-side: reduce across 4 quads (covers all 64 rows of the wi half)
    #pragma unroll
    for (int n = 0; n < 4; n++) {
        float p = gpc[n], q2 = gnc[n];
        p  = fminf(p,  __shfl_xor(p, 16));  p  = fminf(p,  __shfl_xor(p, 32));
        q2 = fmaxf(q2, __shfl_xor(q2, 16)); q2 = fmaxf(q2, __shfl_xor(q2, 32));
        if (quad == 0) {
            const int col = wj * 64 + n * 16 + l15;
            cGp[col][wi] = p; cGn[col][wi] = q2;
        }
    }
    __syncthreads();
    if (t < BT) {                               // waves 0-1: column-side store
        gp_part[(size_t)ib * N + j0 + t] = fminf(cGp[t][0], cGp[t][1]);
        gn_part[(size_t)ib * N + j0 + t] = fmaxf(cGn[t][0], cGn[t][1]);
    } else if (offdiag) {                       // waves 2-3: fold rT rows, row-side store
        const int i = t - BT;
        float p = INFINITY, nn = -INFINITY;
        #pragma unroll
        for (int k = 0; k < 16; k++) {
            p  = fminf(p,  fminf(rT[0][i][k], rT[2][i][k]));
            nn = fmaxf(nn, fmaxf(rT[1][i][k], rT[3][i][k]));
        }
        gp_part[(size_t)jb * N + i0 + i] = p;
        gn_part[(size_t)jb * N + i0 + i] = nn;
    }
}

// ---------------- Kernel 3: fold slots, sqrt, relu, mean — 256 blocks, coalesced ------------
__global__ __launch_bounds__(256) void reduce_kernel(const float* __restrict__ gp_part,
                                                     const float* __restrict__ gn_part,
                                                     float* __restrict__ out) {
    __shared__ float redp[32][5], redn[32][5];
    const int t  = threadIdx.x;
    const int r  = blockIdx.x * 32 + (t & 31);   // 256 blocks x 32 rows
    const int sg = t >> 5;                        // slot group 0..7
    float gp = INFINITY, gn = -INFINITY;
    #pragma unroll
    for (int q = 0; q < 8; q++) {
        const int s = sg * 8 + q;
        gp = fminf(gp, gp_part[(size_t)s * N + r]);
        gn = fmaxf(gn, gn_part[(size_t)s * N + r]);
    }
    gp = fminf(gp, __shfl_xor(gp, 32));
    gn = fmaxf(gn, __shfl_xor(gn, 32));
    const int w = t >> 6;
    if ((t & 63) < 32) { redp[t & 31][w] = gp; redn[t & 31][w] = gn; }
    __syncthreads();
    if (t < 32) {
        const float p  = fminf(fminf(redp[t][0], redp[t][1]), fminf(redp[t][2], redp[t][3]));
        const float nn = fmaxf(fmaxf(redn[t][0], redn[t][1]), fmaxf(redn[t][2], redn[t][3]));
        const float dp = sqrtf(fmaxf(2.0f - 2.0f * p,  EPS));  // hardest_pos distance
        const float dn = sqrtf(fmaxf(2.0f - 2.0f * nn, EPS));  // hardest_neg distance
        const float l  = dp - dn + MARGIN;
        float sum = (l > 0.0f) ? l : 0.0f;
        #pragma unroll
        for (int off = 16; off; off >>= 1) sum += __shfl_down(sum, off);
        if (t == 0) atomicAdd(out, sum * (1.0f / (float)N));
    }
}

extern "C" void kernel_launch(void* const* d_in, const int* in_sizes, int n_in,
                              void* d_out, int out_size, void* d_ws, size_t ws_size,
                              hipStream_t stream) {
    const float* x   = (const float*)d_in[0];
    const int*   lab = (const int*)d_in[1];
    float* out = (float*)d_out;

    char* ws = (char*)d_ws;
    unsigned char* fn8t = (unsigned char*)ws;                       // N*D fp8 = 2 MB (tiled)
    float* gp_part = (float*)(ws + (size_t)N * D);                  // NJB*N floats = 2 MB
    float* gn_part = gp_part + (size_t)NJB * N;                     // NJB*N floats = 2 MB

    normalize_kernel<<<N / 16, 256, 0, stream>>>(x, fn8t, out);
    gram_kernel<<<TOTAL_TRI, 256, 0, stream>>>(fn8t, lab, gp_part, gn_part);
    reduce_kernel<<<N / 32, 256, 0, stream>>>(gp_part, gn_part, out);
}

// Round 13
// 88.087 us; speedup vs baseline: 1.3514x; 1.0393x over previous
//
#include <hip/hip_runtime.h>
#include <hip/hip_bf16.h>
#include <hip/hip_fp8.h>
#include <math.h>

#define N 8192
#define D 256
#define MARGIN 0.3f
#define EPS 1e-12f

#define BT 128                             // block tile (i and j)
#define NJB (N / BT)                       // 64 tile-blocks per dim
#define TOTAL_TRI (NJB * (NJB + 1) / 2)    // 2080 upper-triangle tiles = 8 * 260

typedef __attribute__((ext_vector_type(4))) float floatx4;  // MFMA C/D
typedef long long fp8x8;                                    // 8 fp8 in 2 VGPRs
typedef __attribute__((ext_vector_type(2))) long long llx2; // 16B = two fp8 fragments

static __device__ inline unsigned char f2fp8(float f) {
    __hip_fp8_e4m3 h(f);                   // OCP e4m3fn (gfx950), RNE
    return *reinterpret_cast<unsigned char*>(&h);
}

// fn8t PAIRED layout (R13): row-group g (16 rows), k-step PAIR P=kk>>1 (0..3) -> 1024B block
// at (g*4+P)*1024. Within it, lane p (= quad*16+l15): bytes [p*16, p*16+8) = fragment(g, 2P,
// lane p); bytes [p*16+8, p*16+16) = fragment(g, 2P+1, lane p). One dwordx4 (16B/lane = 1KB
// wave transaction) thus delivers TWO K-steps of lane-correct MFMA fragments -> K-loop request
// count halves vs R12 (the two-term cost model's dominant term).

// ---------------- Kernel 1: L2 normalize -> fp8 e4m3 in paired tiled layout ------------------
__global__ __launch_bounds__(256) void normalize_kernel(const float* __restrict__ x,
                                                        unsigned char* __restrict__ fn8t,
                                                        float* __restrict__ out) {
    __shared__ unsigned char lnorm[16][256];  // 4 KB
    const int g    = blockIdx.x;          // group of 16 rows
    const int t    = threadIdx.x;
    const int w    = t >> 6;
    const int lane = t & 63;
    if (g == 0 && t == 0) out[0] = 0.0f;

    #pragma unroll
    for (int rr = 0; rr < 4; rr++) {
        const int rl  = w * 4 + rr;       // local row 0..15
        const int row = g * 16 + rl;
        float4 v = ((const float4*)(x + (size_t)row * D))[lane];
        float s = v.x * v.x + v.y * v.y + v.z * v.z + v.w * v.w;
        #pragma unroll
        for (int off = 32; off; off >>= 1) s += __shfl_down(s, off);
        s = __shfl(s, 0);
        const float inv = 1.0f / fmaxf(sqrtf(s), 1e-12f);
        uchar4 b;
        b.x = f2fp8(v.x * inv); b.y = f2fp8(v.y * inv);
        b.z = f2fp8(v.z * inv); b.w = f2fp8(v.w * inv);
        *(uchar4*)(&lnorm[rl][lane * 4]) = b;
    }
    __syncthreads();
    // paired tiled write: thread t covers chunk kk = t>>5, two lane-slots p = (t&31)*2 + {0,1}
    const int kk = t >> 5;
    const int pp = (t & 31) * 2;
    unsigned char* base = fn8t + (size_t)g * 4096 + (kk >> 1) * 1024 + (kk & 1) * 8;
    #pragma unroll
    for (int e = 0; e < 2; e++) {
        const int p    = pp + e;
        const int quad = p >> 4;
        const int l15  = p & 15;
        *(fp8x8*)(base + p * 16) = *(const fp8x8*)(&lnorm[l15][kk * 32 + quad * 8]);
    }
}

// ---------------- Kernel 2: triangular MFMA gram (fp8, paired loads), barrier-free -----------
// R13: two-term cost model from R11/R12 (time ~ 0.525*requests + 0.153*KB per wave-tile):
// bf16 64req/64KB=43.4us, fp8 64req/32KB=38.5us -> loop is ~75% REQUEST-bound. This round
// halves requests at constant bytes: paired layout gives 2 K-steps per 16B/lane load ->
// 4 pair-steps x (8 loads + 32 MFMA), 32 requests/wave-tile. Predicted gram ~22us.
// Everything else = champion structure (XCD swizzle, triangular decode, rT epilogue,
// launch_bounds(256,3), reductions on g: post-norm d2=2-2g monotone dec).
__global__ __launch_bounds__(256, 3) void gram_kernel(const unsigned char* __restrict__ fn8t,
                                                      const int* __restrict__ lab,
                                                      float* __restrict__ gp_part,
                                                      float* __restrict__ gn_part) {
    __shared__ float rT[4][BT][17];            // 34816 B; plane = wj*2 + {0:p,1:n}
    __shared__ float cGp[BT][2], cGn[BT][2];   // j-col partials, per wi half

    // XCD swizzle then triangular decode (row-major over jb >= ib)
    const int bidx = blockIdx.x;
    const int idx  = (bidx & 7) * 260 + (bidx >> 3);
    const float c = 2.0f * NJB + 1.0f;
    int ib = (int)((c - sqrtf(c * c - 8.0f * (float)idx)) * 0.5f);
    while (ib > 0 && idx < ib * NJB - ib * (ib - 1) / 2) ib--;
    while (idx >= (ib + 1) * NJB - (ib + 1) * ib / 2) ib++;
    const int jb = ib + (idx - (ib * NJB - ib * (ib - 1) / 2));
    const bool offdiag = (jb > ib);
    const int i0 = ib * BT, j0 = jb * BT;

    const int t    = threadIdx.x;
    const int w    = t >> 6;
    const int lane = t & 63;
    const int wi   = w >> 1, wj = w & 1;        // 2x2 waves, each 64x64
    const int quad = lane >> 4;
    const int l15  = lane & 15;

    // fragment base pointers (row-group stride = 4096 B = 4 pair-blocks)
    const unsigned char* pA[4];
    const unsigned char* pB[4];
    #pragma unroll
    for (int m = 0; m < 4; m++)
        pA[m] = fn8t + ((size_t)(ib * 8 + wi * 4 + m)) * 4096 + lane * 16;
    #pragma unroll
    for (int n = 0; n < 4; n++)
        pB[n] = fn8t + ((size_t)(jb * 8 + wj * 4 + n)) * 4096 + lane * 16;

    floatx4 acc[4][4];
    #pragma unroll
    for (int m = 0; m < 4; m++)
        #pragma unroll
        for (int n = 0; n < 4; n++)
            acc[m][n] = (floatx4){0.f, 0.f, 0.f, 0.f};

    // K-loop: 4 pair-steps; 8 x 1KB wave loads deliver 2 K-steps each; 32 MFMA per pair-step
    #pragma unroll
    for (int P = 0; P < 4; P++) {
        llx2 a2[4], b2[4];
        #pragma unroll
        for (int m = 0; m < 4; m++) a2[m] = *(const llx2*)(pA[m] + P * 1024);
        #pragma unroll
        for (int n = 0; n < 4; n++) b2[n] = *(const llx2*)(pB[n] + P * 1024);
        #pragma unroll
        for (int m = 0; m < 4; m++)
            #pragma unroll
            for (int n = 0; n < 4; n++)
                acc[m][n] = __builtin_amdgcn_mfma_f32_16x16x32_fp8_fp8(a2[m][0], b2[n][0], acc[m][n], 0, 0, 0);
        #pragma unroll
        for (int m = 0; m < 4; m++)
            #pragma unroll
            for (int n = 0; n < 4; n++)
                acc[m][n] = __builtin_amdgcn_mfma_f32_16x16x32_fp8_fp8(a2[m][1], b2[n][1], acc[m][n], 0, 0, 0);
    }

    // ---- epilogue on g. C/D layout: col = l15 (tile col wj*64+n*16+l15), row = quad*4 + reg.
    int labj[4];
    #pragma unroll
    for (int n = 0; n < 4; n++) labj[n] = lab[j0 + wj * 64 + n * 16 + l15];
    float gpc[4], gnc[4];
    #pragma unroll
    for (int n = 0; n < 4; n++) { gpc[n] = INFINITY; gnc[n] = -INFINITY; }

    #pragma unroll
    for (int m = 0; m < 4; m++) {
        const int4 li4 = *(const int4*)(lab + i0 + wi * 64 + m * 16 + quad * 4);
        const int labi[4] = {li4.x, li4.y, li4.z, li4.w};
        #pragma unroll
        for (int r = 0; r < 4; r++) {
            float pr = INFINITY, nr = -INFINITY;
            #pragma unroll
            for (int n = 0; n < 4; n++) {
                const float g = acc[m][n][r];
                const bool same = (labi[r] == labj[n]);
                const float selp = same ? g : INFINITY;
                const float seln = same ? -INFINITY : g;
                pr = fminf(pr, selp);           nr = fmaxf(nr, seln);
                gpc[n] = fminf(gpc[n], selp);   gnc[n] = fmaxf(gnc[n], seln);
            }
            if (offdiag) {                      // row-side: LDS transpose, no shuffle chain
                const int irow = wi * 64 + m * 16 + quad * 4 + r;
                rT[(wj << 1) + 0][irow][l15] = pr;
                rT[(wj << 1) + 1][irow][l15] = nr;
            }
        }
    }
    // column-side: reduce across 4 quads (covers all 64 rows of the wi half)
    #pragma unroll
    for (int n = 0; n < 4; n++) {
        float p = gpc[n], q2 = gnc[n];
        p  = fminf(p,  __shfl_xor(p, 16));  p  = fminf(p,  __shfl_xor(p, 32));
        q2 = fmaxf(q2, __shfl_xor(q2, 16)); q2 = fmaxf(q2, __shfl_xor(q2, 32));
        if (quad == 0) {
            const int col = wj * 64 + n * 16 + l15;
            cGp[col][wi] = p; cGn[col][wi] = q2;
        }
    }
    __syncthreads();
    if (t < BT) {                               // waves 0-1: column-side store
        gp_part[(size_t)ib * N + j0 + t] = fminf(cGp[t][0], cGp[t][1]);
        gn_part[(size_t)ib * N + j0 + t] = fmaxf(cGn[t][0], cGn[t][1]);
    } else if (offdiag) {                       // waves 2-3: fold rT rows, row-side store
        const int i = t - BT;
        float p = INFINITY, nn = -INFINITY;
        #pragma unroll
        for (int k = 0; k < 16; k++) {
            p  = fminf(p,  fminf(rT[0][i][k], rT[2][i][k]));
            nn = fmaxf(nn, fmaxf(rT[1][i][k], rT[3][i][k]));
        }
        gp_part[(size_t)jb * N + i0 + i] = p;
        gn_part[(size_t)jb * N + i0 + i] = nn;
    }
}

// ---------------- Kernel 3: fold slots, sqrt, relu, mean — 256 blocks, coalesced ------------
__global__ __launch_bounds__(256) void reduce_kernel(const float* __restrict__ gp_part,
                                                     const float* __restrict__ gn_part,
                                                     float* __restrict__ out) {
    __shared__ float redp[32][5], redn[32][5];
    const int t  = threadIdx.x;
    const int r  = blockIdx.x * 32 + (t & 31);   // 256 blocks x 32 rows
    const int sg = t >> 5;                        // slot group 0..7
    float gp = INFINITY, gn = -INFINITY;
    #pragma unroll
    for (int q = 0; q < 8; q++) {
        const int s = sg * 8 + q;
        gp = fminf(gp, gp_part[(size_t)s * N + r]);
        gn = fmaxf(gn, gn_part[(size_t)s * N + r]);
    }
    gp = fminf(gp, __shfl_xor(gp, 32));
    gn = fmaxf(gn, __shfl_xor(gn, 32));
    const int w = t >> 6;
    if ((t & 63) < 32) { redp[t & 31][w] = gp; redn[t & 31][w] = gn; }
    __syncthreads();
    if (t < 32) {
        const float p  = fminf(fminf(redp[t][0], redp[t][1]), fminf(redp[t][2], redp[t][3]));
        const float nn = fmaxf(fmaxf(redn[t][0], redn[t][1]), fmaxf(redn[t][2], redn[t][3]));
        const float dp = sqrtf(fmaxf(2.0f - 2.0f * p,  EPS));  // hardest_pos distance
        const float dn = sqrtf(fmaxf(2.0f - 2.0f * nn, EPS));  // hardest_neg distance
        const float l  = dp - dn + MARGIN;
        float sum = (l > 0.0f) ? l : 0.0f;
        #pragma unroll
        for (int off = 16; off; off >>= 1) sum += __shfl_down(sum, off);
        if (t == 0) atomicAdd(out, sum * (1.0f / (float)N));
    }
}

extern "C" void kernel_launch(void* const* d_in, const int* in_sizes, int n_in,
                              void* d_out, int out_size, void* d_ws, size_t ws_size,
                              hipStream_t stream) {
    const float* x   = (const float*)d_in[0];
    const int*   lab = (const int*)d_in[1];
    float* out = (float*)d_out;

    char* ws = (char*)d_ws;
    unsigned char* fn8t = (unsigned char*)ws;                       // N*D fp8 = 2 MB (paired tiled)
    float* gp_part = (float*)(ws + (size_t)N * D);                  // NJB*N floats = 2 MB
    float* gn_part = gp_part + (size_t)NJB * N;                     // NJB*N floats = 2 MB

    normalize_kernel<<<N / 16, 256, 0, stream>>>(x, fn8t, out);
    gram_kernel<<<TOTAL_TRI, 256, 0, stream>>>(fn8t, lab, gp_part, gn_part);
    reduce_kernel<<<N / 32, 256, 0, stream>>>(gp_part, gn_part, out);
}